// Round 3
// baseline (146.120 us; speedup 1.0000x reference)
//
#include <hip/hip_runtime.h>
#include <hip/hip_bf16.h>

// Problem constants (fixed by reference: LS = 8x l0 + 8x l1 + 4x l2)
#define D    52          // dim of in1/in2/out
#define DD   2704        // D*D
#define HH   2000        // cb height
#define DO   52          // output dim
#define NG   20          // h-split groups for M-precompute
#define HPG  (HH/NG)     // 100
#define KP   3328        // padded K = 52 * 64  (j padded to 64 per i-row)
#define NO   64          // padded output dim
#define KS   4           // K-split for main MFMA kernel
#define KT_TOTAL (KP/32) // 104 MFMA k-steps
#define KT_PER   (KT_TOTAL/KS) // 26

typedef __attribute__((ext_vector_type(8))) short short8;
typedef __attribute__((ext_vector_type(4))) float f32x4;

// ws layout (bytes, 256-aligned)
#define PART_BYTES  (NG * DO * DD * 4)        // 11,246,080
#define MTT_BYTES   (NO * KP * 2)             // 425,984
#define OUTP_BYTES  (KS * 4096 * NO * 4)      // 4,194,304
#define PART_OFF    0
#define MTT_OFF     ((PART_BYTES + 255) & ~255)
#define OUTP_OFF    (((MTT_OFF + MTT_BYTES) + 255) & ~255)

static __device__ __forceinline__ unsigned short f2bf(float f) {
    __hip_bfloat16 h = __float2bfloat16(f);   // RNE; compiler fuses to v_cvt_pk_bf16_f32
    return __builtin_bit_cast(unsigned short, h);
}

// ---------------------------------------------------------------------------
// K1: part[g][o][ij] = sum_{h in group g} W[o,h]*cb[h,ij]
// block 256 = 64 ij-lanes x 4 o-groups (13 o's each); W via wave-uniform s_load
// grid (43, NG) = 860 blocks -> ~3.4 waves/SIMD
// ---------------------------------------------------------------------------
__global__ __launch_bounds__(256) void k_partial(
    const float* __restrict__ cb, const float* __restrict__ W,
    float* __restrict__ part) {
    int lane  = threadIdx.x & 63;
    int og    = __builtin_amdgcn_readfirstlane(threadIdx.x >> 6);  // 0..3, SGPR
    int ij    = blockIdx.x * 64 + lane;
    int g     = blockIdx.y;
    int obase = og * 13;

    float acc[13];
#pragma unroll
    for (int c = 0; c < 13; ++c) acc[c] = 0.f;

    bool valid = (ij < DD);
    const float* cbp = cb + ij;
    int h0 = g * HPG;
#pragma unroll 4
    for (int hh = 0; hh < HPG; ++hh) {
        int h = h0 + hh;
        float cbv = valid ? cbp[(size_t)h * DD] : 0.f;
#pragma unroll
        for (int c = 0; c < 13; ++c)
            acc[c] = fmaf(W[(obase + c) * HH + h], cbv, acc[c]);  // s_load operand
    }
    if (valid) {
#pragma unroll
        for (int c = 0; c < 13; ++c)
            part[((size_t)g * DO + obase + c) * DD + ij] = acc[c];
    }
}

// ---------------------------------------------------------------------------
// K2: reduce partials + pack M^T into bf16, B-fragment-friendly layout:
//     mtT[o][i*64 + j] = bf16( sum_g part[g][o][i*52+j] ), zero-padded
// ---------------------------------------------------------------------------
__global__ __launch_bounds__(256) void k_reduce_mt(
    const float* __restrict__ part, unsigned short* __restrict__ mtT) {
    int idx = blockIdx.x * 256 + threadIdx.x;   // over NO*KP = 212992
    if (idx >= NO * KP) return;
    int o  = idx / KP;
    int kp = idx - o * KP;
    int i  = kp >> 6, j = kp & 63;
    float s = 0.f;
    if (o < DO && j < D) {
        size_t base = (size_t)o * DD + i * D + j;
#pragma unroll
        for (int g = 0; g < NG; ++g) s += part[(size_t)g * (DO * DD) + base];
    }
    mtT[idx] = f2bf(s);
}

// ---------------------------------------------------------------------------
// K3: MFMA main:  outp[ks][b][o] = sum_{k in split ks} outer_bf16[b,k]*mtT[o,k]
// block 256 = 4 waves (one 16-col o-tile each) x 16 batches; grid (B/16, KS)
// A-frag built on the fly: a[e] = bf16(in1[b,i] * in2pad[b,j0+e])
// ---------------------------------------------------------------------------
__global__ __launch_bounds__(256) void k_main_mfma(
    const float* __restrict__ in1, const float* __restrict__ in2,
    const unsigned short* __restrict__ mtT, float* __restrict__ outp) {
    __shared__ float sh1[16][53];   // in1 rows (padded: stride 53 -> conflict-free)
    __shared__ float sh2[16][68];   // in2 rows padded to 64 j (stride 68 -> 2-way max)

    int lane = threadIdx.x & 63;
    int wv   = __builtin_amdgcn_readfirstlane(threadIdx.x >> 6);  // o-tile id
    int b0   = blockIdx.x * 16;
    int ks   = blockIdx.y;
    int o0   = wv * 16;

    for (int t = threadIdx.x; t < 16 * 64; t += 256) {
        int r = t >> 6, j = t & 63;
        sh2[r][j] = (j < D) ? in2[(size_t)(b0 + r) * D + j] : 0.f;
    }
    for (int t = threadIdx.x; t < 16 * D; t += 256) {
        int r = t / D, i = t - r * D;
        sh1[r][i] = in1[(size_t)(b0 + r) * D + i];
    }
    __syncthreads();

    int r   = lane & 15;          // batch row within tile
    int kg  = lane >> 4;          // k-group 0..3
    int oc  = o0 + r;             // this lane's B column
    const unsigned short* bp = mtT + (size_t)oc * KP + ks * KT_PER * 32 + kg * 8;

    f32x4 acc = {0.f, 0.f, 0.f, 0.f};
#pragma unroll 2
    for (int t = 0; t < KT_PER; ++t) {
        int kt    = ks * KT_PER + t;
        int i     = kt >> 1;
        int j0    = (kt & 1) * 32 + kg * 8;
        float f1  = sh1[r][i];
        short8 a;
#pragma unroll
        for (int e = 0; e < 8; ++e)
            a[e] = (short)f2bf(f1 * sh2[r][j0 + e]);
        short8 b = *reinterpret_cast<const short8*>(bp + (size_t)t * 32);
        acc = __builtin_amdgcn_mfma_f32_16x16x32_bf16(a, b, acc, 0, 0, 0);
    }

    // C/D layout: col = lane&15, row = (lane>>4)*4 + reg
#pragma unroll
    for (int q = 0; q < 4; ++q) {
        int row = kg * 4 + q;
        outp[((size_t)ks * 4096 + b0 + row) * NO + o0 + r] = acc[q];
    }
}

// ---------------------------------------------------------------------------
// K4: out[b][o] = sum_ks outp[ks][b][o]
// ---------------------------------------------------------------------------
__global__ __launch_bounds__(256) void k_out(
    const float* __restrict__ outp, float* __restrict__ out, int B) {
    int idx = blockIdx.x * 256 + threadIdx.x;
    if (idx >= B * DO) return;
    int b = idx / DO, o = idx - b * DO;
    float s = 0.f;
#pragma unroll
    for (int g = 0; g < KS; ++g) s += outp[((size_t)g * B + b) * NO + o];
    out[idx] = s;
}

// ---------------------------------------------------------------------------
extern "C" void kernel_launch(void* const* d_in, const int* in_sizes, int n_in,
                              void* d_out, int out_size, void* d_ws, size_t ws_size,
                              hipStream_t stream) {
    const float* in1 = (const float*)d_in[0];
    const float* in2 = (const float*)d_in[1];
    const float* cb  = (const float*)d_in[2];
    const float* W   = (const float*)d_in[3];
    float* out = (float*)d_out;

    int B = in_sizes[0] / D;  // 4096

    char* ws = (char*)d_ws;
    float*          part = (float*)(ws + PART_OFF);
    unsigned short* mtT  = (unsigned short*)(ws + MTT_OFF);
    float*          outp = (float*)(ws + OUTP_OFF);

    hipLaunchKernelGGL(k_partial, dim3((DD + 63) / 64, NG), dim3(256), 0,
                       stream, cb, W, part);
    hipLaunchKernelGGL(k_reduce_mt, dim3((NO * KP + 255) / 256), dim3(256), 0,
                       stream, part, mtT);
    hipLaunchKernelGGL(k_main_mfma, dim3(B / 16, KS), dim3(256), 0,
                       stream, in1, in2, mtT, outp);
    hipLaunchKernelGGL(k_out, dim3((B * DO + 255) / 256), dim3(256), 0,
                       stream, outp, out, B);
}

// Round 4
// 119.378 us; speedup vs baseline: 1.2240x; 1.2240x over previous
//
#include <hip/hip_runtime.h>
#include <hip/hip_bf16.h>

// Problem constants (fixed by reference: LS = 8x l0 + 8x l1 + 4x l2)
#define D    52          // dim of in1/in2/out
#define DD   2704        // D*D
#define HH   2000        // cb height
#define DO   52          // output dim
#define KP   3328        // padded K for main GEMM = 52 * 64
#define NO   64          // padded output dim
#define KS   4           // K-split for main MFMA kernel
#define KT_TOTAL (KP/32) // 104
#define KT_PER   (KT_TOTAL/KS) // 26
#define MG   16          // K-split groups for M-precompute GEMM
#define KCH  128         // padded K per group (16*128 = 2048 >= 2000)
#define WHP  2048        // padded W row length

typedef __attribute__((ext_vector_type(8))) short short8;
typedef __attribute__((ext_vector_type(4))) float f32x4;

// ws layout (bytes)
#define WB_OFF    0
#define WB_BYTES  (NO * WHP * 2)              //    262,144
#define MTP_OFF   (WB_OFF + WB_BYTES)
#define MTP_BYTES (MG * DD * NO * 4)          // 11,075,584
#define MTT_OFF   (MTP_OFF + MTP_BYTES)
#define MTT_BYTES (NO * KP * 2)               //    425,984
#define OUTP_OFF  (MTT_OFF + MTT_BYTES)
#define OUTP_BYTES (KS * 4096 * NO * 4)       //  4,194,304

static __device__ __forceinline__ unsigned short f2bf(float f) {
    __hip_bfloat16 h = __float2bfloat16(f);
    return __builtin_bit_cast(unsigned short, h);
}

// ---------------------------------------------------------------------------
// K_A: pack W -> bf16, zero-padded: Wb[o][h], o<64, h<2048
// ---------------------------------------------------------------------------
__global__ __launch_bounds__(256) void k_packw(
    const float* __restrict__ W, unsigned short* __restrict__ Wb) {
    int idx = blockIdx.x * 256 + threadIdx.x;
    if (idx >= NO * WHP) return;
    int o = idx >> 11, h = idx & (WHP - 1);
    float v = (o < DO && h < HH) ? W[o * HH + h] : 0.f;
    Wb[idx] = f2bf(v);
}

// ---------------------------------------------------------------------------
// K_B: M-precompute via MFMA.  mtp[g][ij][o] = sum_{h in grp g} cb[h,ij]*W[o,h]
// block 256 = 4 waves; block tile = 64 ij x 64 o; K-chunk 128 (4 k-steps).
// cb staged transposed in LDS fp32 [64 ij][33] (conflict-free), cvt to bf16.
// Fragment roles identical to the verified k_main_mfma usage.
// ---------------------------------------------------------------------------
__global__ __launch_bounds__(256) void k_mgemm(
    const float* __restrict__ cb, const unsigned short* __restrict__ Wb,
    float* __restrict__ mtp) {
    __shared__ float shAT[64][33];   // [ij_local][h_local] fp32
    int lane = threadIdx.x & 63;
    int w    = __builtin_amdgcn_readfirstlane(threadIdx.x >> 6);
    int r    = lane & 15;
    int kg   = lane >> 4;
    int ij0  = blockIdx.x * 64;
    int g    = blockIdx.y;

    f32x4 acc[4];
#pragma unroll
    for (int nt = 0; nt < 4; ++nt) acc[nt] = (f32x4){0.f, 0.f, 0.f, 0.f};

    int srow = threadIdx.x >> 6;       // 0..3
    int scol = threadIdx.x & 63;       // ij offset
    int sij  = ij0 + scol;
    bool ijv = (sij < DD);

#pragma unroll
    for (int kt = 0; kt < KCH / 32; ++kt) {
        int h0 = g * KCH + kt * 32;
        __syncthreads();   // previous reads done before overwrite
#pragma unroll
        for (int p = 0; p < 8; ++p) {
            int row = srow + p * 4;                 // h_local 0..31
            int h = h0 + row;
            float v = (h < HH && ijv) ? cb[(size_t)h * DD + sij] : 0.f;
            shAT[scol][row] = v;
        }
        __syncthreads();

        int myij = w * 16 + r;
        short8 a;
#pragma unroll
        for (int e = 0; e < 8; ++e)
            a[e] = (short)f2bf(shAT[myij][kg * 8 + e]);
#pragma unroll
        for (int nt = 0; nt < 4; ++nt) {
            short8 b = *reinterpret_cast<const short8*>(
                Wb + (size_t)(nt * 16 + r) * WHP + g * KCH + kt * 32 + kg * 8);
            acc[nt] = __builtin_amdgcn_mfma_f32_16x16x32_bf16(a, b, acc[nt], 0, 0, 0);
        }
    }

    // D layout: col = lane&15 (o), row = kg*4 + q (ij_local within wave tile)
#pragma unroll
    for (int nt = 0; nt < 4; ++nt) {
#pragma unroll
        for (int q = 0; q < 4; ++q) {
            int ij = ij0 + w * 16 + kg * 4 + q;
            if (ij < DD)
                mtp[((size_t)g * DD + ij) * NO + nt * 16 + r] = acc[nt][q];
        }
    }
}

// ---------------------------------------------------------------------------
// K_C: reduce partials over g and pack to mtT[o][i*64+j] bf16 (zero-padded).
// One block per i (52 blocks). Coalesced reads (lane = o), LDS transpose.
// ---------------------------------------------------------------------------
__global__ __launch_bounds__(256) void k_reduce_pack(
    const float* __restrict__ mtp, unsigned short* __restrict__ mtT) {
    __shared__ float sh[D][NO + 1];
    int i = blockIdx.x;

    for (int t = threadIdx.x; t < D * NO; t += 256) {
        int row = t >> 6, o = t & 63;          // row = j (ij_local)
        size_t base = (size_t)(i * D + row) * NO + o;
        float s = 0.f;
#pragma unroll
        for (int g = 0; g < MG; ++g) s += mtp[(size_t)g * DD * NO + base];
        sh[row][o] = s;
    }
    __syncthreads();

    // write: for each o row, 64 j's (j>=52 zero)
    int j  = threadIdx.x & 63;
    int o0 = threadIdx.x >> 6;
    for (int o = o0; o < NO; o += 4) {
        float v = (j < D) ? sh[j][o] : 0.f;
        mtT[(size_t)o * KP + i * 64 + j] = f2bf(v);
    }
}

// ---------------------------------------------------------------------------
// K_D: MFMA main:  outp[ks][b][o] = sum_{k in split ks} outer_bf16[b,k]*mtT[o,k]
// (unchanged from round 3 — verified)
// ---------------------------------------------------------------------------
__global__ __launch_bounds__(256) void k_main_mfma(
    const float* __restrict__ in1, const float* __restrict__ in2,
    const unsigned short* __restrict__ mtT, float* __restrict__ outp) {
    __shared__ float sh1[16][53];
    __shared__ float sh2[16][68];

    int lane = threadIdx.x & 63;
    int wv   = __builtin_amdgcn_readfirstlane(threadIdx.x >> 6);
    int b0   = blockIdx.x * 16;
    int ks   = blockIdx.y;
    int o0   = wv * 16;

    for (int t = threadIdx.x; t < 16 * 64; t += 256) {
        int r = t >> 6, j = t & 63;
        sh2[r][j] = (j < D) ? in2[(size_t)(b0 + r) * D + j] : 0.f;
    }
    for (int t = threadIdx.x; t < 16 * D; t += 256) {
        int r = t / D, i = t - r * D;
        sh1[r][i] = in1[(size_t)(b0 + r) * D + i];
    }
    __syncthreads();

    int r   = lane & 15;
    int kg  = lane >> 4;
    int oc  = o0 + r;
    const unsigned short* bp = mtT + (size_t)oc * KP + ks * KT_PER * 32 + kg * 8;

    f32x4 acc = {0.f, 0.f, 0.f, 0.f};
#pragma unroll 2
    for (int t = 0; t < KT_PER; ++t) {
        int kt    = ks * KT_PER + t;
        int i     = kt >> 1;
        int j0    = (kt & 1) * 32 + kg * 8;
        float f1  = sh1[r][i];
        short8 a;
#pragma unroll
        for (int e = 0; e < 8; ++e)
            a[e] = (short)f2bf(f1 * sh2[r][j0 + e]);
        short8 b = *reinterpret_cast<const short8*>(bp + (size_t)t * 32);
        acc = __builtin_amdgcn_mfma_f32_16x16x32_bf16(a, b, acc, 0, 0, 0);
    }

#pragma unroll
    for (int q = 0; q < 4; ++q) {
        int row = kg * 4 + q;
        outp[((size_t)ks * 4096 + b0 + row) * NO + o0 + r] = acc[q];
    }
}

// ---------------------------------------------------------------------------
// K_E: out[b][o] = sum_ks outp[ks][b][o]
// ---------------------------------------------------------------------------
__global__ __launch_bounds__(256) void k_out(
    const float* __restrict__ outp, float* __restrict__ out, int B) {
    int idx = blockIdx.x * 256 + threadIdx.x;
    if (idx >= B * DO) return;
    int b = idx / DO, o = idx - b * DO;
    float s = 0.f;
#pragma unroll
    for (int g = 0; g < KS; ++g) s += outp[((size_t)g * B + b) * NO + o];
    out[idx] = s;
}

// ---------------------------------------------------------------------------
extern "C" void kernel_launch(void* const* d_in, const int* in_sizes, int n_in,
                              void* d_out, int out_size, void* d_ws, size_t ws_size,
                              hipStream_t stream) {
    const float* in1 = (const float*)d_in[0];
    const float* in2 = (const float*)d_in[1];
    const float* cb  = (const float*)d_in[2];
    const float* W   = (const float*)d_in[3];
    float* out = (float*)d_out;

    int B = in_sizes[0] / D;  // 4096

    char* ws = (char*)d_ws;
    unsigned short* Wb   = (unsigned short*)(ws + WB_OFF);
    float*          mtp  = (float*)(ws + MTP_OFF);
    unsigned short* mtT  = (unsigned short*)(ws + MTT_OFF);
    float*          outp = (float*)(ws + OUTP_OFF);

    hipLaunchKernelGGL(k_packw, dim3((NO * WHP + 255) / 256), dim3(256), 0,
                       stream, W, Wb);
    hipLaunchKernelGGL(k_mgemm, dim3((DD + 63) / 64, MG), dim3(256), 0,
                       stream, cb, Wb, mtp);
    hipLaunchKernelGGL(k_reduce_pack, dim3(D), dim3(256), 0,
                       stream, mtp, mtT);
    hipLaunchKernelGGL(k_main_mfma, dim3(B / 16, KS), dim3(256), 0,
                       stream, in1, in2, mtT, outp);
    hipLaunchKernelGGL(k_out, dim3((B * DO + 255) / 256), dim3(256), 0,
                       stream, outp, out, B);
}

// Round 6
// 106.637 us; speedup vs baseline: 1.3703x; 1.1195x over previous
//
#include <hip/hip_runtime.h>
#include <hip/hip_bf16.h>

// Problem constants (fixed by reference: LS = 8x l0 + 8x l1 + 4x l2)
#define D    52          // dim of in1/in2/out
#define DD   2704        // D*D
#define HH   2000        // cb height
#define DO   52          // output dim
#define KP   3328        // padded K for main GEMM = 52 * 64
#define NO   64          // padded output dim
#define KS   4           // K-split for main MFMA kernel
#define KT_TOTAL (KP/32) // 104
#define KT_PER   (KT_TOTAL/KS) // 26
#define MG   16          // K-split groups for M-precompute GEMM
#define KCH  128         // padded K per group (16*128 = 2048 >= 2000)
#define WHP  2048        // padded W row length

typedef __attribute__((ext_vector_type(8))) short short8;
typedef __attribute__((ext_vector_type(4))) float f32x4;

// ws layout (bytes, 256-aligned)
#define WB_OFF     0
#define WB_BYTES   (NO * WHP * 2)              //    262,144
#define MTP_OFF    (WB_OFF + WB_BYTES)
#define MTP_BYTES  (MG * NO * DD * 4)          // 11,075,584
#define MTB_OFF    (MTP_OFF + MTP_BYTES)
#define MTB_BYTES  (KT_TOTAL * NO * 32 * 2)    //    425,984
#define OUTP_OFF   (MTB_OFF + MTB_BYTES)
#define OUTP_BYTES (KS * 4096 * NO * 4)        //  4,194,304

static __device__ __forceinline__ unsigned short f2bf(float f) {
    __hip_bfloat16 h = __float2bfloat16(f);
    return __builtin_bit_cast(unsigned short, h);
}

// ---------------------------------------------------------------------------
// K_A: pack W -> bf16, zero-padded: Wb[o][h], o<64, h<2048
// ---------------------------------------------------------------------------
__global__ __launch_bounds__(256) void k_packw(
    const float* __restrict__ W, unsigned short* __restrict__ Wb) {
    int idx = blockIdx.x * 256 + threadIdx.x;
    if (idx >= NO * WHP) return;
    int o = idx >> 11, h = idx & (WHP - 1);
    float v = (o < DO && h < HH) ? W[o * HH + h] : 0.f;
    Wb[idx] = f2bf(v);
}

// ---------------------------------------------------------------------------
// K_B: M-precompute via MFMA.  mtp[g][o][ij] = sum_{h in grp g} W[o,h]*cb[h,ij]
// Roles: A = W (M=o), B = cb-tile (N=ij). Per-lane addressing identical to the
// verified round-3/4 fragment code; only the operand slots are swapped.
// ---------------------------------------------------------------------------
__global__ __launch_bounds__(256) void k_mgemm(
    const float* __restrict__ cb, const unsigned short* __restrict__ Wb,
    float* __restrict__ mtp) {
    __shared__ float shAT[64][33];   // [ij_local][h_local], stride 33 -> 2-way max
    int lane = threadIdx.x & 63;
    int w    = __builtin_amdgcn_readfirstlane(threadIdx.x >> 6);
    int r    = lane & 15;
    int kg   = lane >> 4;
    int ij0  = blockIdx.x * 64;
    int g    = blockIdx.y;

    f32x4 acc[4];
#pragma unroll
    for (int mt = 0; mt < 4; ++mt) acc[mt] = (f32x4){0.f, 0.f, 0.f, 0.f};

    int srow = threadIdx.x >> 6;       // 0..3
    int scol = threadIdx.x & 63;       // ij offset
    int sij  = ij0 + scol;
    bool ijv = (sij < DD);

#pragma unroll
    for (int kt = 0; kt < KCH / 32; ++kt) {
        int h0 = g * KCH + kt * 32;
        __syncthreads();   // previous reads done before overwrite
#pragma unroll
        for (int p = 0; p < 8; ++p) {
            int row = srow + p * 4;                 // h_local 0..31
            int h = h0 + row;
            float v = (h < HH && ijv) ? cb[(size_t)h * DD + sij] : 0.f;
            shAT[scol][row] = v;
        }
        __syncthreads();

        // B-frag (cb): b[e] = B[k=kg*8+e][n=ij], wave owns ij = ij0+w*16+r
        short8 bf;
#pragma unroll
        for (int e = 0; e < 8; ++e)
            bf[e] = (short)f2bf(shAT[w * 16 + r][kg * 8 + e]);
        // A-frags (W): a[e] = Wb[o][h], o = mt*16+r, contiguous 16B
#pragma unroll
        for (int mt = 0; mt < 4; ++mt) {
            short8 a = *reinterpret_cast<const short8*>(
                Wb + (size_t)(mt * 16 + r) * WHP + g * KCH + kt * 32 + kg * 8);
            acc[mt] = __builtin_amdgcn_mfma_f32_16x16x32_bf16(a, bf, acc[mt], 0, 0, 0);
        }
    }

    // D layout: col(lane&15) = n = ij, row(kg*4+q) = m = o
    int ij = ij0 + w * 16 + r;
    if (ij < DD) {
#pragma unroll
        for (int mt = 0; mt < 4; ++mt) {
#pragma unroll
            for (int q = 0; q < 4; ++q) {
                int o = mt * 16 + kg * 4 + q;
                mtp[((size_t)g * NO + o) * DD + ij] = acc[mt][q];
            }
        }
    }
}

// ---------------------------------------------------------------------------
// K_C: reduce partials over g + pack blocked-B bf16:
//   mtB[kt][o][kg][e] = bf16( M[o, i*52+j] ),  k = i*64+j (padded, j>=52 -> 0)
// grid (13, 64): 832 blocks, fully coalesced reads.
// ---------------------------------------------------------------------------
__global__ __launch_bounds__(256) void k_reduce_mtb(
    const float* __restrict__ mtp, unsigned short* __restrict__ mtB) {
    int k = blockIdx.x * 256 + threadIdx.x;   // 0..3327 (= KP exactly)
    int o = blockIdx.y;
    int i = k >> 6, j = k & 63;
    float s = 0.f;
    if (j < D) {
        size_t base = (size_t)o * DD + i * D + j;
#pragma unroll
        for (int g = 0; g < MG; ++g) s += mtp[(size_t)g * (NO * DD) + base];
    }
    mtB[((size_t)(k >> 5) * NO + o) * 32 + ((k >> 3) & 3) * 8 + (k & 7)] = f2bf(s);
}

// ---------------------------------------------------------------------------
// K_D: MFMA main: outp[ks][b][o] = sum_{k in split ks} outer_bf16[b,k]*M[o,k]
// B from blocked mtB: per (kt, o-tile) one contiguous 1KB wave read.
// sh2 stride 69 -> max 2-way LDS conflict (free).
// ---------------------------------------------------------------------------
__global__ __launch_bounds__(256) void k_main_mfma(
    const float* __restrict__ in1, const float* __restrict__ in2,
    const unsigned short* __restrict__ mtB, float* __restrict__ outp) {
    __shared__ float sh1[16][53];
    __shared__ float sh2[16][69];

    int lane = threadIdx.x & 63;
    int wv   = __builtin_amdgcn_readfirstlane(threadIdx.x >> 6);
    int b0   = blockIdx.x * 16;
    int ks   = blockIdx.y;
    int o0   = wv * 16;

    for (int t = threadIdx.x; t < 16 * 64; t += 256) {
        int r = t >> 6, j = t & 63;
        sh2[r][j] = (j < D) ? in2[(size_t)(b0 + r) * D + j] : 0.f;
    }
    for (int t = threadIdx.x; t < 16 * D; t += 256) {
        int r = t / D, i = t - r * D;
        sh1[r][i] = in1[(size_t)(b0 + r) * D + i];
    }
    __syncthreads();

    int r  = lane & 15;
    int kg = lane >> 4;
    const unsigned short* bp =
        mtB + ((size_t)(ks * KT_PER) * NO + o0 + r) * 32 + kg * 8;

    f32x4 acc = {0.f, 0.f, 0.f, 0.f};
#pragma unroll 2
    for (int t = 0; t < KT_PER; ++t) {
        int kt   = ks * KT_PER + t;
        int i    = kt >> 1;
        int j0   = (kt & 1) * 32 + kg * 8;
        float f1 = sh1[r][i];
        short8 a;
#pragma unroll
        for (int e = 0; e < 8; ++e)
            a[e] = (short)f2bf(f1 * sh2[r][j0 + e]);
        short8 b = *reinterpret_cast<const short8*>(bp + (size_t)t * (NO * 32));
        acc = __builtin_amdgcn_mfma_f32_16x16x32_bf16(a, b, acc, 0, 0, 0);
    }

    // C/D: col = lane&15 (o), row = kg*4+q (batch)
#pragma unroll
    for (int q = 0; q < 4; ++q) {
        int row = kg * 4 + q;
        outp[((size_t)ks * 4096 + b0 + row) * NO + o0 + r] = acc[q];
    }
}

// ---------------------------------------------------------------------------
// K_E: out[b][o] = sum_ks outp[ks][b][o]
// ---------------------------------------------------------------------------
__global__ __launch_bounds__(256) void k_out(
    const float* __restrict__ outp, float* __restrict__ out, int B) {
    int idx = blockIdx.x * 256 + threadIdx.x;
    if (idx >= B * DO) return;
    int b = idx / DO, o = idx - b * DO;
    float s = 0.f;
#pragma unroll
    for (int g = 0; g < KS; ++g) s += outp[((size_t)g * B + b) * NO + o];
    out[idx] = s;
}

// ---------------------------------------------------------------------------
extern "C" void kernel_launch(void* const* d_in, const int* in_sizes, int n_in,
                              void* d_out, int out_size, void* d_ws, size_t ws_size,
                              hipStream_t stream) {
    const float* in1 = (const float*)d_in[0];
    const float* in2 = (const float*)d_in[1];
    const float* cb  = (const float*)d_in[2];
    const float* W   = (const float*)d_in[3];
    float* out = (float*)d_out;

    int B = in_sizes[0] / D;  // 4096

    char* ws = (char*)d_ws;
    unsigned short* Wb   = (unsigned short*)(ws + WB_OFF);
    float*          mtp  = (float*)(ws + MTP_OFF);
    unsigned short* mtB  = (unsigned short*)(ws + MTB_OFF);
    float*          outp = (float*)(ws + OUTP_OFF);

    hipLaunchKernelGGL(k_packw, dim3((NO * WHP + 255) / 256), dim3(256), 0,
                       stream, W, Wb);
    hipLaunchKernelGGL(k_mgemm, dim3((DD + 63) / 64, MG), dim3(256), 0,
                       stream, cb, Wb, mtp);
    hipLaunchKernelGGL(k_reduce_mtb, dim3(KP / 256, NO), dim3(256), 0,
                       stream, mtp, mtB);
    hipLaunchKernelGGL(k_main_mfma, dim3(B / 16, KS), dim3(256), 0,
                       stream, in1, in2, mtB, outp);
    hipLaunchKernelGGL(k_out, dim3((B * DO + 255) / 256), dim3(256), 0,
                       stream, outp, out, B);
}